// Round 1
// baseline (345.190 us; speedup 1.0000x reference)
//
#include <hip/hip_runtime.h>
#include <hip/hip_bf16.h>
#include <math.h>

// Problem constants
#define N_T   16
#define BSZ   128
#define DDIM  4096
#define KROWS (N_T * BSZ)          // 2048
#define CHW   (3 * 64 * 64)        // 12288
#define S_PIC (BSZ * CHW)          // 1572864
#define T_MSE (N_T * S_PIC)        // 25165824
#define KPOS  (KROWS * (N_T - 1))  // 30720

#define MSE_BLOCKS  3072           // 16 slabs x 192 blocks

typedef short  bf16x8 __attribute__((ext_vector_type(8)));   // 8 bf16 = 4 VGPRs
typedef float  f32x4  __attribute__((ext_vector_type(4)));

// ---------------- reductions ----------------
__device__ __forceinline__ float waveReduceSum(float v) {
    for (int off = 32; off > 0; off >>= 1) v += __shfl_down(v, off, 64);
    return v;
}
__device__ __forceinline__ float blockReduceSum(float v) {
    __shared__ float s[8];
    int lane = threadIdx.x & 63, wid = threadIdx.x >> 6;
    v = waveReduceSum(v);
    if (lane == 0) s[wid] = v;
    __syncthreads();
    int nw = (blockDim.x + 63) >> 6;
    v = (threadIdx.x < nw) ? s[threadIdx.x] : 0.0f;
    if (wid == 0) v = waveReduceSum(v);
    return v;   // valid in thread 0
}

// ---------------- MSE block body (m13 copy pattern) ----------------
// Slab n, block bx: 8192 contiguous floats at n*S_PIC + bx*8192.
__device__ __forceinline__ void mse_block(const float* __restrict__ pic,
                                          const float* __restrict__ dec,
                                          float* __restrict__ acc,
                                          int n, int bx) {
    const size_t off = (size_t)n * S_PIC + (size_t)bx * 8192 + threadIdx.x * 4;
    const ptrdiff_t doff = (ptrdiff_t)(((n + 1) & (N_T - 1)) - n) * S_PIC;
    const float* p = pic + off;
    const float* d = dec + off + doff;
    float s0 = 0.f, s1 = 0.f, s2 = 0.f, s3 = 0.f;
#pragma unroll
    for (int k = 0; k < 8; k++) {
        float4 a = *(const float4*)(p + k * 1024);
        float4 b = *(const float4*)(d + k * 1024);
        float dx = a.x - b.x, dy = a.y - b.y, dz = a.z - b.z, dw = a.w - b.w;
        s0 += dx * dx; s1 += dy * dy; s2 += dz * dz; s3 += dw * dw;
    }
    float sum = (s0 + s1) + (s2 + s3);
    sum = blockReduceSum(sum);
    if (threadIdx.x == 0) atomicAdd(acc, sum);
}

// ---------------- K2: row normalization of h -> bf16 (+acc zeroing) --------
__global__ void norm_kernel(const float* __restrict__ h,
                            __hip_bfloat16* __restrict__ hb,
                            float* __restrict__ acc, int zero_acc) {
    // Fold the accumulator/counter memset into this kernel (one fewer
    // dispatch). Safe: norm precedes all acc consumers in-stream.
    if (zero_acc && blockIdx.x == 0 && threadIdx.x < 64)
        acc[threadIdx.x] = 0.0f;

    const int row = blockIdx.x;
    const float* r = h + (size_t)row * DDIM;
    float ss = 0.0f;
    for (int k = threadIdx.x * 8; k < DDIM; k += blockDim.x * 8) {
        float4 v0 = *(const float4*)(r + k);
        float4 v1 = *(const float4*)(r + k + 4);
        ss += v0.x * v0.x + v0.y * v0.y + v0.z * v0.z + v0.w * v0.w;
        ss += v1.x * v1.x + v1.y * v1.y + v1.z * v1.z + v1.w * v1.w;
    }
    ss = blockReduceSum(ss);
    __shared__ float scale_s;
    if (threadIdx.x == 0) scale_s = 1.0f / fmaxf(sqrtf(ss), 1e-8f);
    __syncthreads();
    const float sc = scale_s;
    __hip_bfloat16* ob = hb + (size_t)row * DDIM;
    for (int k = threadIdx.x * 8; k < DDIM; k += blockDim.x * 8) {
        float4 v0 = *(const float4*)(r + k);
        float4 v1 = *(const float4*)(r + k + 4);
        __hip_bfloat16 t[8];
        t[0] = __float2bfloat16(v0.x * sc); t[1] = __float2bfloat16(v0.y * sc);
        t[2] = __float2bfloat16(v0.z * sc); t[3] = __float2bfloat16(v0.w * sc);
        t[4] = __float2bfloat16(v1.x * sc); t[5] = __float2bfloat16(v1.y * sc);
        t[6] = __float2bfloat16(v1.z * sc); t[7] = __float2bfloat16(v1.w * sc);
        *(bf16x8*)(ob + k) = *(const bf16x8*)t;   // 16 B store
    }
}

// ---------------- Mega kernel: fused GEMM (split-K=NKZ) + MSE ----------------
// Blocks [0, NKZ*256): m97-structure bf16 MFMA GEMM, S = 2 * X @ X^T into
// NKZ partial buffers. NKZ=4 recreates the measured-874TF residency point
// (1024 blocks ~ 4 GEMM blocks/CU -> MFMA pipes of co-resident blocks
// interleave; at NKZ=2 the structure only reaches ~320 TF).
// Blocks [NKZ*256, +MSE_BLOCKS): HBM-streaming MSE, hides under the GEMM span.
template<int NKZ>
__global__ __launch_bounds__(256) void mega_kernel(const ushort* __restrict__ X,
                                                   float* __restrict__ Cpart,
                                                   const float* __restrict__ pic,
                                                   const float* __restrict__ dec,
                                                   float* __restrict__ acc) {
    __shared__ ushort As[128 * 32];   // 8 KB, row-major 128x32
    __shared__ ushort Bs[128 * 32];   // 8 KB
    constexpr int NG = NKZ * 256;
    int bid = blockIdx.x;

    if (bid >= NG) {
        const int t = bid - NG;
        mse_block(pic, dec, acc, t & (N_T - 1), t >> 4);
        return;
    }

    // ---- GEMM path ----
    // XCD-aware bijective swizzle (NG % 8 == 0): contiguous tile chunk per XCD
    // for L2 locality on the hbuf panels.
    bid = (bid & 7) * (NG >> 3) + (bid >> 3);

    const int kz = bid >> 8;                 // split-K slice
    const int bi = (bid >> 4) & 15, bj = bid & 15;
    const int tid  = threadIdx.x;
    const int wave = tid >> 6, lane = tid & 63;
    const int wm = wave >> 1, wn = wave & 1;        // 2x2 wave grid
    const int quad = lane >> 4, l16 = lane & 15;

    f32x4 acc_r[4][4];
#pragma unroll
    for (int i = 0; i < 4; i++)
#pragma unroll
        for (int j = 0; j < 4; j++) acc_r[i][j] = (f32x4){0.f, 0.f, 0.f, 0.f};

    // Staging: 8 chunks of 16 rows per tile; wave w loads chunks {w, w+4}.
    // Lane l -> row l/4, col (l%4)*8 within chunk; LDS dest is wave-uniform
    // base + lane*16 B, matching the row-major layout exactly.
    const int srow = lane >> 2;          // 0..15
    const int scol = (lane & 3) * 8;     // 0,8,16,24
    const ushort* Ag0 = X + (size_t)(bi * 128 + wave * 16       + srow) * DDIM + scol;
    const ushort* Ag1 = X + (size_t)(bi * 128 + (wave + 4) * 16 + srow) * DDIM + scol;
    const ushort* Bg0 = X + (size_t)(bj * 128 + wave * 16       + srow) * DDIM + scol;
    const ushort* Bg1 = X + (size_t)(bj * 128 + (wave + 4) * 16 + srow) * DDIM + scol;
    ushort* Al0 = As + wave * 512;
    ushort* Al1 = As + (wave + 4) * 512;
    ushort* Bl0 = Bs + wave * 512;
    ushort* Bl1 = Bs + (wave + 4) * 512;

    constexpr int KS = DDIM / NKZ;
    const int k0 = kz * KS, k1 = k0 + KS;
    for (int kk = k0; kk < k1; kk += 32) {
        __syncthreads();   // previous iter's LDS reads done before overwrite
        __builtin_amdgcn_global_load_lds(
            (const __attribute__((address_space(1))) unsigned int*)(Ag0 + kk),
            (__attribute__((address_space(3))) unsigned int*)Al0, 16, 0, 0);
        __builtin_amdgcn_global_load_lds(
            (const __attribute__((address_space(1))) unsigned int*)(Ag1 + kk),
            (__attribute__((address_space(3))) unsigned int*)Al1, 16, 0, 0);
        __builtin_amdgcn_global_load_lds(
            (const __attribute__((address_space(1))) unsigned int*)(Bg0 + kk),
            (__attribute__((address_space(3))) unsigned int*)Bl0, 16, 0, 0);
        __builtin_amdgcn_global_load_lds(
            (const __attribute__((address_space(1))) unsigned int*)(Bg1 + kk),
            (__attribute__((address_space(3))) unsigned int*)Bl1, 16, 0, 0);
        __syncthreads();   // drains vmcnt(0): staging visible

        bf16x8 a[4], b[4];
#pragma unroll
        for (int t = 0; t < 4; t++)   // A[m = l16 + tile][k = quad*8 + 0..7]
            a[t] = *(const bf16x8*)(As + (wm * 64 + t * 16 + l16) * 32 + quad * 8);
#pragma unroll
        for (int t = 0; t < 4; t++)
            b[t] = *(const bf16x8*)(Bs + (wn * 64 + t * 16 + l16) * 32 + quad * 8);
#pragma unroll
        for (int mt = 0; mt < 4; mt++)
#pragma unroll
            for (int nt = 0; nt < 4; nt++)
                acc_r[mt][nt] = __builtin_amdgcn_mfma_f32_16x16x32_bf16(
                    a[mt], b[nt], acc_r[mt][nt], 0, 0, 0);
    }

    // Epilogue: C/D layout col = lane&15, row = quad*4 + reg. Writes 2*acc
    // (the /TEMP) into this K-slice's partial buffer.
    float* Cp = Cpart + (size_t)kz * KROWS * KROWS;
#pragma unroll
    for (int mt = 0; mt < 4; mt++) {
#pragma unroll
        for (int r = 0; r < 4; r++) {
            const int row = bi * 128 + wm * 64 + mt * 16 + quad * 4 + r;
            float* o = Cp + (size_t)row * KROWS + bj * 128 + wn * 64 + l16;
#pragma unroll
            for (int nt = 0; nt < 4; nt++) o[nt * 16] = 2.0f * acc_r[mt][nt][r];
        }
    }
}

// ---------------- standalone MSE (fallback sequential path) ----------------
__global__ __launch_bounds__(256) void mse_kernel(const float* __restrict__ pic,
                                                  const float* __restrict__ dec,
                                                  float* __restrict__ acc) {
    mse_block(pic, dec, acc, blockIdx.y, blockIdx.x);
}

// ---------------- K4: per-row fixed-shift LSE + positives (+finalize) -------
// All simmat entries are 2*cos_sim <= 2.0, so logsumexp can use a FIXED shift
// of 2.0: exp(s-2) in [e^-4, 1], no overflow, f32-exact enough. This deletes
// the max pass + one block reduction. The last block to finish (device-scope
// counter) also performs the finalize -> one fewer dispatch.
template<int NKZ>
__global__ void lse_kernel(const float* __restrict__ Cpart,
                           float* __restrict__ acc,
                           float* __restrict__ out) {
    const int i = blockIdx.x;
    __shared__ float srow[KROWS];      // 8 KB
    const float* r0 = Cpart + (size_t)i * KROWS;
    for (int j = threadIdx.x * 4; j < KROWS; j += blockDim.x * 4) {
        float4 s = *(const float4*)(r0 + j);
#pragma unroll
        for (int p = 1; p < NKZ; p++) {
            float4 b = *(const float4*)(r0 + (size_t)p * KROWS * KROWS + j);
            s.x += b.x; s.y += b.y; s.z += b.z; s.w += b.w;
        }
        *(float4*)(srow + j) = s;
    }
    __syncthreads();

    const int ires = i & (BSZ - 1);
    float se = 0.0f;
    for (int j = threadIdx.x; j < KROWS; j += blockDim.x)
        if ((j & (BSZ - 1)) != ires) se += __expf(srow[j] - 2.0f);
    se = blockReduceSum(se);

    if (threadIdx.x == 0) {
        const float neg_lse = 2.0f + __logf(se);
        float loss = 0.0f;
#pragma unroll
        for (int t = 0; t < N_T; t++) {
            const int j = ires + t * BSZ;
            if (j == i) continue;
            const float x = neg_lse - srow[j];   // logaddexp(L,p)-p = softplus(L-p)
            loss += (x > 0.0f) ? (x + log1pf(expf(-x))) : log1pf(expf(x));
        }
        atomicAdd(acc + 1, loss);
        __threadfence();
        const int old = atomicAdd((int*)acc + 8, 1);
        if (old == KROWS - 1) {
            // Atomic RMW read-back guarantees device-scope freshness.
            const float mse = atomicAdd(acc + 0, 0.0f);
            const float lh  = atomicAdd(acc + 1, 0.0f);
            out[0] = mse / (float)T_MSE + lh / (float)KPOS;
        }
    }
}

extern "C" void kernel_launch(void* const* d_in, const int* in_sizes, int n_in,
                              void* d_out, int out_size, void* d_ws, size_t ws_size,
                              hipStream_t stream) {
    const float* pic = (const float*)d_in[0];
    float* dec = (float*)d_in[1];
    const float* h = (const float*)d_in[2];
    float* out = (float*)d_out;

    float* acc = (float*)d_ws;           // acc[0]=mse_sum, acc[1]=loss_h_sum, int acc[8]=done-counter
    const size_t hbuf_bytes = (size_t)KROWS * DDIM * sizeof(__hip_bfloat16);   // 16 MB
    const size_t part_bytes = (size_t)KROWS * KROWS * sizeof(float);           // 16.78 MB

    if (ws_size >= 256 + hbuf_bytes + 4 * part_bytes) {
        // Split-K=4: 1024 GEMM blocks (~4/CU) -> m97-measured residency point.
        __hip_bfloat16* hbuf = (__hip_bfloat16*)((char*)d_ws + 256);
        float* Cpart = (float*)((char*)d_ws + 256 + hbuf_bytes);
        norm_kernel<<<KROWS, 256, 0, stream>>>(h, hbuf, acc, 1);
        mega_kernel<4><<<4 * 256 + MSE_BLOCKS, 256, 0, stream>>>(
            (const ushort*)hbuf, Cpart, pic, dec, acc);
        lse_kernel<4><<<KROWS, 256, 0, stream>>>(Cpart, acc, out);
    } else if (ws_size >= 256 + hbuf_bytes + 2 * part_bytes) {
        // Split-K=2 overlapped (previous-best structure).
        __hip_bfloat16* hbuf = (__hip_bfloat16*)((char*)d_ws + 256);
        float* Cpart = (float*)((char*)d_ws + 256 + hbuf_bytes);
        norm_kernel<<<KROWS, 256, 0, stream>>>(h, hbuf, acc, 1);
        mega_kernel<2><<<2 * 256 + MSE_BLOCKS, 256, 0, stream>>>(
            (const ushort*)hbuf, Cpart, pic, dec, acc);
        lse_kernel<2><<<KROWS, 256, 0, stream>>>(Cpart, acc, out);
    } else {
        // Fallback: dec buffer as scratch. MSE must fully consume dec BEFORE
        // norm/gemm overwrite it -> strictly sequential kernels.
        hipMemsetAsync(d_ws, 0, 256, stream);
        __hip_bfloat16* hbuf = (__hip_bfloat16*)dec;
        float* Cpart = (float*)((char*)dec + hbuf_bytes);
        mse_kernel<<<dim3(MSE_BLOCKS / N_T, N_T), 256, 0, stream>>>(pic, dec, acc);
        norm_kernel<<<KROWS, 256, 0, stream>>>(h, hbuf, acc, 0);
        mega_kernel<2><<<2 * 256, 256, 0, stream>>>(
            (const ushort*)hbuf, Cpart, pic, dec, acc);
        lse_kernel<2><<<KROWS, 256, 0, stream>>>(Cpart, acc, out);
    }
}